// Round 1
// baseline (1367.452 us; speedup 1.0000x reference)
//
#include <hip/hip_runtime.h>
#include <hip/hip_bf16.h>

#define NN 50000
#define NE 600000
#define DD 128
#define NR 8

__device__ __forceinline__ unsigned short f2bf(float f) {
  __hip_bfloat16 h = __float2bfloat16(f);
  return *reinterpret_cast<unsigned short*>(&h);
}

// C[n,o] = sum_d h[n,d] * Wm[d,o]   for Wm in {W[0..7], Wself}
// grid.x: row tiles of 64; grid.y in [0,9): r<8 -> write bf16 hr, r==8 -> write f32 out + bias
__global__ __launch_bounds__(256) void transform_kernel(
    const float* __restrict__ h, const int* __restrict__ ids,
    const float* __restrict__ Wrel, const float* __restrict__ Wself,
    const float* __restrict__ bias,
    __hip_bfloat16* __restrict__ hr, float* __restrict__ outSelf)
{
  __shared__ float Ast[32][64];   // [k][row]  8 KB  (transposed A tile)
  __shared__ float Bs[32][DD];    // [k][col] 16 KB

  const int r = blockIdx.y;
  const int rowBase = blockIdx.x * 64;
  const float* __restrict__ Wm = (r < NR) ? (Wrel + (size_t)r * DD * DD) : Wself;
  const int tid = threadIdx.x;
  const int tx = tid & 31;   // cols tx*4 .. tx*4+3
  const int ty = tid >> 5;   // rows ty*8 .. ty*8+7

  // A staging: thread loads 8 consecutive k of one row
  const int a_row = tid >> 2;
  const int a_k0  = (tid & 3) * 8;
  const int grow_a = rowBase + a_row;
  const bool aValid = grow_a < NN;
  const int srcRow = aValid ? (ids ? ids[grow_a] : grow_a) : 0;
  const float* __restrict__ hrow = h + (size_t)srcRow * DD;

  // B staging: thread loads 16 consecutive floats of one W row
  const int b_k = tid >> 3;
  const int b_c = (tid & 7) * 16;

  float acc[8][4];
#pragma unroll
  for (int i = 0; i < 8; ++i)
#pragma unroll
    for (int j = 0; j < 4; ++j) acc[i][j] = 0.f;

  for (int k0 = 0; k0 < DD; k0 += 32) {
    __syncthreads();
    float4 a0, a1;
    if (aValid) {
      a0 = *reinterpret_cast<const float4*>(hrow + k0 + a_k0);
      a1 = *reinterpret_cast<const float4*>(hrow + k0 + a_k0 + 4);
    } else {
      a0 = make_float4(0.f, 0.f, 0.f, 0.f); a1 = a0;
    }
    Ast[a_k0 + 0][a_row] = a0.x; Ast[a_k0 + 1][a_row] = a0.y;
    Ast[a_k0 + 2][a_row] = a0.z; Ast[a_k0 + 3][a_row] = a0.w;
    Ast[a_k0 + 4][a_row] = a1.x; Ast[a_k0 + 5][a_row] = a1.y;
    Ast[a_k0 + 6][a_row] = a1.z; Ast[a_k0 + 7][a_row] = a1.w;

    const float* wsrc = Wm + (size_t)(k0 + b_k) * DD + b_c;
    float4 q0 = reinterpret_cast<const float4*>(wsrc)[0];
    float4 q1 = reinterpret_cast<const float4*>(wsrc)[1];
    float4 q2 = reinterpret_cast<const float4*>(wsrc)[2];
    float4 q3 = reinterpret_cast<const float4*>(wsrc)[3];
    *reinterpret_cast<float4*>(&Bs[b_k][b_c])      = q0;
    *reinterpret_cast<float4*>(&Bs[b_k][b_c + 4])  = q1;
    *reinterpret_cast<float4*>(&Bs[b_k][b_c + 8])  = q2;
    *reinterpret_cast<float4*>(&Bs[b_k][b_c + 12]) = q3;
    __syncthreads();

#pragma unroll
    for (int kk = 0; kk < 32; ++kk) {
      const float4 av0 = *reinterpret_cast<const float4*>(&Ast[kk][ty * 8]);
      const float4 av1 = *reinterpret_cast<const float4*>(&Ast[kk][ty * 8 + 4]);
      const float4 bv  = *reinterpret_cast<const float4*>(&Bs[kk][tx * 4]);
      const float a_[8] = {av0.x, av0.y, av0.z, av0.w, av1.x, av1.y, av1.z, av1.w};
#pragma unroll
      for (int i = 0; i < 8; ++i) {
        acc[i][0] = fmaf(a_[i], bv.x, acc[i][0]);
        acc[i][1] = fmaf(a_[i], bv.y, acc[i][1]);
        acc[i][2] = fmaf(a_[i], bv.z, acc[i][2]);
        acc[i][3] = fmaf(a_[i], bv.w, acc[i][3]);
      }
    }
  }

  if (r < NR) {
#pragma unroll
    for (int i = 0; i < 8; ++i) {
      const int grow = rowBase + ty * 8 + i;
      if (grow < NN) {
        ushort4 w;
        w.x = f2bf(acc[i][0]); w.y = f2bf(acc[i][1]);
        w.z = f2bf(acc[i][2]); w.w = f2bf(acc[i][3]);
        *reinterpret_cast<ushort4*>(
            reinterpret_cast<unsigned short*>(hr) +
            ((size_t)r * NN + grow) * DD + tx * 4) = w;
      }
    }
  } else {
    const float4 bv = *reinterpret_cast<const float4*>(bias + tx * 4);
#pragma unroll
    for (int i = 0; i < 8; ++i) {
      const int grow = rowBase + ty * 8 + i;
      if (grow < NN) {
        float4 o;
        o.x = acc[i][0] + bv.x; o.y = acc[i][1] + bv.y;
        o.z = acc[i][2] + bv.z; o.w = acc[i][3] + bv.w;
        *reinterpret_cast<float4*>(outSelf + (size_t)grow * DD + tx * 4) = o;
      }
    }
  }
}

// one wave per edge: read hr[etype,src] row (bf16, 256B coalesced), atomicAdd into out[dst]
__global__ __launch_bounds__(256) void scatter_kernel(
    const __hip_bfloat16* __restrict__ hr,
    const int* __restrict__ src, const int* __restrict__ dst,
    const int* __restrict__ et, float* __restrict__ out)
{
  const int gid = blockIdx.x * 256 + threadIdx.x;
  const int e = gid >> 6;
  const int lane = threadIdx.x & 63;
  if (e >= NE) return;
  const int s = src[e];
  const int d = dst[e];
  const int r = et[e];
  const unsigned u = *reinterpret_cast<const unsigned*>(
      reinterpret_cast<const unsigned short*>(hr) +
      ((size_t)r * NN + s) * DD + lane * 2);
  const float v0 = __uint_as_float((u & 0xffffu) << 16);
  const float v1 = __uint_as_float(u & 0xffff0000u);
  float* o = out + (size_t)d * DD + lane * 2;
  atomicAdd(o, v0);
  atomicAdd(o + 1, v1);
}

extern "C" void kernel_launch(void* const* d_in, const int* in_sizes, int n_in,
                              void* d_out, int out_size, void* d_ws, size_t ws_size,
                              hipStream_t stream) {
  const int*   node_ids = (const int*)d_in[0];
  const int*   src   = (const int*)d_in[1];
  const int*   dst   = (const int*)d_in[2];
  const int*   etype = (const int*)d_in[3];
  const float* emb   = (const float*)d_in[4];
  const float* W1    = (const float*)d_in[5];
  const float* Ws1   = (const float*)d_in[6];
  const float* b1    = (const float*)d_in[7];
  const float* W2    = (const float*)d_in[8];
  const float* Ws2   = (const float*)d_in[9];
  const float* b2    = (const float*)d_in[10];

  // ws layout: hr bf16 [R*NN*DD] = 102.4 MB, then h1 f32 [NN*DD] = 25.6 MB
  __hip_bfloat16* hr = (__hip_bfloat16*)d_ws;
  float* h1 = (float*)((char*)d_ws + (size_t)NR * NN * DD * sizeof(__hip_bfloat16));

  dim3 tgrid((NN + 63) / 64, NR + 1);
  const int sblocks = (NE * 64) / 256;  // 150000

  // layer 1: h0 = emb[node_ids]
  transform_kernel<<<tgrid, 256, 0, stream>>>(emb, node_ids, W1, Ws1, b1, hr, h1);
  scatter_kernel<<<sblocks, 256, 0, stream>>>(hr, src, dst, etype, h1);
  // layer 2
  transform_kernel<<<tgrid, 256, 0, stream>>>(h1, nullptr, W2, Ws2, b2, hr, (float*)d_out);
  scatter_kernel<<<sblocks, 256, 0, stream>>>(hr, src, dst, etype, (float*)d_out);
}

// Round 2
// 665.935 us; speedup vs baseline: 2.0534x; 2.0534x over previous
//
#include <hip/hip_runtime.h>
#include <hip/hip_bf16.h>

#define NN 50000
#define NE 600000
#define DD 128
#define NR 8

__device__ __forceinline__ unsigned short f2bf(float f) {
  __hip_bfloat16 h = __float2bfloat16(f);
  return *reinterpret_cast<unsigned short*>(&h);
}

// ---------------- transform (unchanged from R0) ----------------
// C[n,o] = sum_d h[n,d] * Wm[d,o]   for Wm in {W[0..7], Wself}
__global__ __launch_bounds__(256) void transform_kernel(
    const float* __restrict__ h, const int* __restrict__ ids,
    const float* __restrict__ Wrel, const float* __restrict__ Wself,
    const float* __restrict__ bias,
    __hip_bfloat16* __restrict__ hr, float* __restrict__ outSelf)
{
  __shared__ float Ast[32][64];   // [k][row]
  __shared__ float Bs[32][DD];    // [k][col]

  const int r = blockIdx.y;
  const int rowBase = blockIdx.x * 64;
  const float* __restrict__ Wm = (r < NR) ? (Wrel + (size_t)r * DD * DD) : Wself;
  const int tid = threadIdx.x;
  const int tx = tid & 31;
  const int ty = tid >> 5;

  const int a_row = tid >> 2;
  const int a_k0  = (tid & 3) * 8;
  const int grow_a = rowBase + a_row;
  const bool aValid = grow_a < NN;
  const int srcRow = aValid ? (ids ? ids[grow_a] : grow_a) : 0;
  const float* __restrict__ hrow = h + (size_t)srcRow * DD;

  const int b_k = tid >> 3;
  const int b_c = (tid & 7) * 16;

  float acc[8][4];
#pragma unroll
  for (int i = 0; i < 8; ++i)
#pragma unroll
    for (int j = 0; j < 4; ++j) acc[i][j] = 0.f;

  for (int k0 = 0; k0 < DD; k0 += 32) {
    __syncthreads();
    float4 a0, a1;
    if (aValid) {
      a0 = *reinterpret_cast<const float4*>(hrow + k0 + a_k0);
      a1 = *reinterpret_cast<const float4*>(hrow + k0 + a_k0 + 4);
    } else {
      a0 = make_float4(0.f, 0.f, 0.f, 0.f); a1 = a0;
    }
    Ast[a_k0 + 0][a_row] = a0.x; Ast[a_k0 + 1][a_row] = a0.y;
    Ast[a_k0 + 2][a_row] = a0.z; Ast[a_k0 + 3][a_row] = a0.w;
    Ast[a_k0 + 4][a_row] = a1.x; Ast[a_k0 + 5][a_row] = a1.y;
    Ast[a_k0 + 6][a_row] = a1.z; Ast[a_k0 + 7][a_row] = a1.w;

    const float* wsrc = Wm + (size_t)(k0 + b_k) * DD + b_c;
    float4 q0 = reinterpret_cast<const float4*>(wsrc)[0];
    float4 q1 = reinterpret_cast<const float4*>(wsrc)[1];
    float4 q2 = reinterpret_cast<const float4*>(wsrc)[2];
    float4 q3 = reinterpret_cast<const float4*>(wsrc)[3];
    *reinterpret_cast<float4*>(&Bs[b_k][b_c])      = q0;
    *reinterpret_cast<float4*>(&Bs[b_k][b_c + 4])  = q1;
    *reinterpret_cast<float4*>(&Bs[b_k][b_c + 8])  = q2;
    *reinterpret_cast<float4*>(&Bs[b_k][b_c + 12]) = q3;
    __syncthreads();

#pragma unroll
    for (int kk = 0; kk < 32; ++kk) {
      const float4 av0 = *reinterpret_cast<const float4*>(&Ast[kk][ty * 8]);
      const float4 av1 = *reinterpret_cast<const float4*>(&Ast[kk][ty * 8 + 4]);
      const float4 bv  = *reinterpret_cast<const float4*>(&Bs[kk][tx * 4]);
      const float a_[8] = {av0.x, av0.y, av0.z, av0.w, av1.x, av1.y, av1.z, av1.w};
#pragma unroll
      for (int i = 0; i < 8; ++i) {
        acc[i][0] = fmaf(a_[i], bv.x, acc[i][0]);
        acc[i][1] = fmaf(a_[i], bv.y, acc[i][1]);
        acc[i][2] = fmaf(a_[i], bv.z, acc[i][2]);
        acc[i][3] = fmaf(a_[i], bv.w, acc[i][3]);
      }
    }
  }

  if (r < NR) {
#pragma unroll
    for (int i = 0; i < 8; ++i) {
      const int grow = rowBase + ty * 8 + i;
      if (grow < NN) {
        ushort4 w;
        w.x = f2bf(acc[i][0]); w.y = f2bf(acc[i][1]);
        w.z = f2bf(acc[i][2]); w.w = f2bf(acc[i][3]);
        *reinterpret_cast<ushort4*>(
            reinterpret_cast<unsigned short*>(hr) +
            ((size_t)r * NN + grow) * DD + tx * 4) = w;
      }
    }
  } else {
    const float4 bv = *reinterpret_cast<const float4*>(bias + tx * 4);
#pragma unroll
    for (int i = 0; i < 8; ++i) {
      const int grow = rowBase + ty * 8 + i;
      if (grow < NN) {
        float4 o;
        o.x = acc[i][0] + bv.x; o.y = acc[i][1] + bv.y;
        o.z = acc[i][2] + bv.z; o.w = acc[i][3] + bv.w;
        *reinterpret_cast<float4*>(outSelf + (size_t)grow * DD + tx * 4) = o;
      }
    }
  }
}

// ---------------- CSR build (once per call, reused for both layers) ----------------

// deg[dst] += 1
__global__ __launch_bounds__(256) void hist_kernel(
    const int* __restrict__ dst, int* __restrict__ deg)
{
  const int e = blockIdx.x * 256 + threadIdx.x;
  if (e < NE) atomicAdd(&deg[dst[e]], 1);
}

// single-block 2-pass exclusive scan of deg[0..NN) -> offsets[0..NN]
// also rewrites deg[i] := start offset (used as fill cursor). NOT restrict-aliased.
__global__ __launch_bounds__(256) void scan_kernel(int* deg, int* offsets)
{
  __shared__ int sums[256];
  const int t = threadIdx.x;
  const int per = (NN + 255) / 256;           // 196
  const int b = t * per;
  const int e = min(b + per, NN);
  int s = 0;
  for (int i = b; i < e; ++i) s += deg[i];
  sums[t] = s;
  __syncthreads();
  if (t == 0) {
    int run = 0;
    for (int i = 0; i < 256; ++i) { int v = sums[i]; sums[i] = run; run += v; }
  }
  __syncthreads();
  int run = sums[t];
  for (int i = b; i < e; ++i) {
    int v = deg[i];
    offsets[i] = run;
    deg[i] = run;        // cursor start
    run += v;
  }
  if (e == NN && b < NN) offsets[NN] = run;   // last thread with work writes total
}

// eidx[pos] = packed hr-row index (r*NN + src), bucketed by dst
__global__ __launch_bounds__(256) void fill_kernel(
    const int* __restrict__ src, const int* __restrict__ dst,
    const int* __restrict__ et, int* __restrict__ cursor,
    int* __restrict__ eidx)
{
  const int e = blockIdx.x * 256 + threadIdx.x;
  if (e < NE) {
    const int pos = atomicAdd(&cursor[dst[e]], 1);
    eidx[pos] = et[e] * NN + src[e];
  }
}

// ---------------- pull-mode aggregation: no atomics ----------------
// one wave per node; lane owns 2 columns; out[n] += sum over in-edges of hr[row]
__global__ __launch_bounds__(256) void aggregate_kernel(
    const __hip_bfloat16* __restrict__ hr,
    const int* __restrict__ offsets, const int* __restrict__ eidx,
    float* __restrict__ out)
{
  const int node = blockIdx.x * 4 + (threadIdx.x >> 6);
  const int lane = threadIdx.x & 63;
  if (node >= NN) return;
  const int beg = offsets[node];
  const int end = offsets[node + 1];
  const unsigned short* __restrict__ hrp =
      reinterpret_cast<const unsigned short*>(hr);

  float a0 = 0.f, a1 = 0.f;
  int e = beg;
  for (; e + 1 < end; e += 2) {
    const int r0 = eidx[e], r1 = eidx[e + 1];
    const unsigned u0 = *reinterpret_cast<const unsigned*>(hrp + (size_t)r0 * DD + lane * 2);
    const unsigned u1 = *reinterpret_cast<const unsigned*>(hrp + (size_t)r1 * DD + lane * 2);
    a0 += __uint_as_float((u0 & 0xffffu) << 16) + __uint_as_float((u1 & 0xffffu) << 16);
    a1 += __uint_as_float(u0 & 0xffff0000u) + __uint_as_float(u1 & 0xffff0000u);
  }
  if (e < end) {
    const int r0 = eidx[e];
    const unsigned u0 = *reinterpret_cast<const unsigned*>(hrp + (size_t)r0 * DD + lane * 2);
    a0 += __uint_as_float((u0 & 0xffffu) << 16);
    a1 += __uint_as_float(u0 & 0xffff0000u);
  }

  float2* o = reinterpret_cast<float2*>(out + (size_t)node * DD + lane * 2);
  float2 v = *o;
  v.x += a0; v.y += a1;
  *o = v;
}

extern "C" void kernel_launch(void* const* d_in, const int* in_sizes, int n_in,
                              void* d_out, int out_size, void* d_ws, size_t ws_size,
                              hipStream_t stream) {
  const int*   node_ids = (const int*)d_in[0];
  const int*   src   = (const int*)d_in[1];
  const int*   dst   = (const int*)d_in[2];
  const int*   etype = (const int*)d_in[3];
  const float* emb   = (const float*)d_in[4];
  const float* W1    = (const float*)d_in[5];
  const float* Ws1   = (const float*)d_in[6];
  const float* b1    = (const float*)d_in[7];
  const float* W2    = (const float*)d_in[8];
  const float* Ws2   = (const float*)d_in[9];
  const float* b2    = (const float*)d_in[10];

  // ws layout:
  //   hr      bf16 [R*NN*DD]   102.4 MB
  //   h1      f32  [NN*DD]      25.6 MB
  //   offsets i32  [NN+1]       0.2 MB
  //   deg     i32  [NN]         0.2 MB   (histogram -> fill cursor)
  //   eidx    i32  [NE]         2.4 MB
  char* p = (char*)d_ws;
  __hip_bfloat16* hr = (__hip_bfloat16*)p;            p += (size_t)NR * NN * DD * 2;
  float* h1          = (float*)p;                     p += (size_t)NN * DD * 4;
  int* offsets       = (int*)p;                       p += (size_t)(NN + 1) * 4;
  int* deg           = (int*)p;                       p += (size_t)NN * 4;
  int* eidx          = (int*)p;

  const int eb = (NE + 255) / 256;                    // 2344
  dim3 tgrid((NN + 63) / 64, NR + 1);
  const int ab = (NN + 3) / 4;                        // 12500

  // CSR build (graph is identical for both layers)
  hipMemsetAsync(deg, 0, (size_t)NN * 4, stream);
  hist_kernel<<<eb, 256, 0, stream>>>(dst, deg);
  scan_kernel<<<1, 256, 0, stream>>>(deg, offsets);
  fill_kernel<<<eb, 256, 0, stream>>>(src, dst, etype, deg, eidx);

  // layer 1
  transform_kernel<<<tgrid, 256, 0, stream>>>(emb, node_ids, W1, Ws1, b1, hr, h1);
  aggregate_kernel<<<ab, 256, 0, stream>>>(hr, offsets, eidx, h1);
  // layer 2
  transform_kernel<<<tgrid, 256, 0, stream>>>(h1, nullptr, W2, Ws2, b2, hr, (float*)d_out);
  aggregate_kernel<<<ab, 256, 0, stream>>>(hr, offsets, eidx, (float*)d_out);
}

// Round 4
// 371.271 us; speedup vs baseline: 3.6832x; 1.7937x over previous
//
#include <hip/hip_runtime.h>
#include <hip/hip_bf16.h>

#define NN 50000
#define NE 600000
#define DD 128
#define NR 8

typedef __attribute__((ext_vector_type(8))) short bf16x8;
typedef __attribute__((ext_vector_type(4))) float f32x4;

__device__ __forceinline__ unsigned short f2bf(float f) {
  __hip_bfloat16 h = __float2bfloat16(f);
  return *reinterpret_cast<unsigned short*>(&h);
}
__device__ __forceinline__ unsigned pk2(float lo, float hi) {
  return (unsigned)f2bf(lo) | ((unsigned)f2bf(hi) << 16);
}
__device__ __forceinline__ float bflo(unsigned u) { return __uint_as_float(u << 16); }
__device__ __forceinline__ float bfhi(unsigned u) { return __uint_as_float(u & 0xffff0000u); }

// ---------------- weight transpose+convert: WT[m][o][d] = bf16(W[m][d][o]) ----------------
__global__ __launch_bounds__(128) void convw_kernel(
    const float* __restrict__ W1, const float* __restrict__ Ws1,
    const float* __restrict__ W2, const float* __restrict__ Ws2,
    unsigned short* __restrict__ WT)
{
  const int m = blockIdx.y, o = blockIdx.x, d = threadIdx.x;
  const float* src;
  if (m < 8)       src = W1 + (size_t)m * DD * DD;
  else if (m == 8) src = Ws1;
  else if (m < 17) src = W2 + (size_t)(m - 9) * DD * DD;
  else             src = Ws2;
  WT[(size_t)m * DD * DD + o * DD + d] = f2bf(src[(size_t)d * DD + o]);
}

// ---------------- MFMA transform ----------------
// grid (ceil(NN/64), 9). r<8: hr[r][n][:] = bf16(h @ W_r). r==8: out[n][:] = h @ Wself + b.
template<int AF32, int OUTF32>
__global__ __launch_bounds__(256) void transform_mfma(
    const void* __restrict__ hin, const int* __restrict__ ids,
    const unsigned short* __restrict__ WT,   // this layer's 9 mats, [m][o][d] bf16
    const float* __restrict__ bias,
    unsigned short* __restrict__ hr,
    void* __restrict__ outSelf)
{
  __shared__ __align__(16) char ldsW[DD * DD * 2];   // 32 KB, XOR-swizzled

  const int r = blockIdx.y;
  const int rowBase = blockIdx.x * 64;
  const int tid = threadIdx.x;

  // stage WT[r] -> LDS: 2048 x 16B chunks (32 KB), swizzle byte ^= (o&7)<<4
  {
    const unsigned short* wsrc = WT + (size_t)r * DD * DD;
#pragma unroll
    for (int j = 0; j < 8; ++j) {
      const int i = tid + j * 256;          // i in [0, 2048)
      const int o = i >> 4, seg = i & 15;   // row o: 16 chunks of 16B = 256B
      uint4 v = *reinterpret_cast<const uint4*>(wsrc + o * DD + seg * 8);
      const int dstB = ((o << 8) + (seg << 4)) ^ ((o & 7) << 4);
      *reinterpret_cast<uint4*>(ldsW + dstB) = v;
    }
  }

  const int lane = tid & 63;
  const int w = tid >> 6;
  const int c = lane & 15;          // n selector (B col) / o-local (A row) selector
  const int g = lane >> 4;          // k group
  const int n = rowBase + w * 16 + c;
  const int nld = (n < NN) ? n : (NN - 1);

  // h rows -> SECOND mfma operand (B role, col = lane&15)
  bf16x8 hfrag[4];
  if (AF32) {
    const int srcRow = ids[nld];
    const float* hrow = (const float*)hin + (size_t)srcRow * DD;
#pragma unroll
    for (int ks = 0; ks < 4; ++ks) {
      const float4 x = *reinterpret_cast<const float4*>(hrow + ks * 32 + g * 8);
      const float4 y = *reinterpret_cast<const float4*>(hrow + ks * 32 + g * 8 + 4);
      uint4 u;
      u.x = pk2(x.x, x.y); u.y = pk2(x.z, x.w);
      u.z = pk2(y.x, y.y); u.w = pk2(y.z, y.w);
      hfrag[ks] = *reinterpret_cast<bf16x8*>(&u);
    }
  } else {
    const unsigned short* hrow = (const unsigned short*)hin + (size_t)nld * DD;
#pragma unroll
    for (int ks = 0; ks < 4; ++ks) {
      uint4 u = *reinterpret_cast<const uint4*>(hrow + ks * 32 + g * 8);
      hfrag[ks] = *reinterpret_cast<bf16x8*>(&u);
    }
  }

  __syncthreads();

  f32x4 acc[8];
#pragma unroll
  for (int t = 0; t < 8; ++t) acc[t] = (f32x4){0.f, 0.f, 0.f, 0.f};

#pragma unroll
  for (int ks = 0; ks < 4; ++ks) {
#pragma unroll
    for (int t = 0; t < 8; ++t) {
      const int addr = (((t * 16 + c) << 8) + (ks << 6) + (g << 4)) ^ ((c & 7) << 4);
      bf16x8 a = *reinterpret_cast<const bf16x8*>(ldsW + addr);
      acc[t] = __builtin_amdgcn_mfma_f32_16x16x32_bf16(a, hfrag[ks], acc[t], 0, 0, 0);
    }
  }

  if (n >= NN) return;

  if (r < NR) {
    unsigned short* dst = hr + ((size_t)r * NN + n) * DD;
#pragma unroll
    for (int t = 0; t < 8; ++t) {
      const int o0 = t * 16 + g * 4;
      uint2 u;
      u.x = pk2(acc[t][0], acc[t][1]);
      u.y = pk2(acc[t][2], acc[t][3]);
      *reinterpret_cast<uint2*>(dst + o0) = u;
    }
  } else if (OUTF32) {
    float* dst = (float*)outSelf + (size_t)n * DD;
#pragma unroll
    for (int t = 0; t < 8; ++t) {
      const int o0 = t * 16 + g * 4;
      const float4 bv = *reinterpret_cast<const float4*>(bias + o0);
      float4 o;
      o.x = acc[t][0] + bv.x; o.y = acc[t][1] + bv.y;
      o.z = acc[t][2] + bv.z; o.w = acc[t][3] + bv.w;
      *reinterpret_cast<float4*>(dst + o0) = o;
    }
  } else {
    unsigned short* dst = (unsigned short*)outSelf + (size_t)n * DD;
#pragma unroll
    for (int t = 0; t < 8; ++t) {
      const int o0 = t * 16 + g * 4;
      const float4 bv = *reinterpret_cast<const float4*>(bias + o0);
      uint2 u;
      u.x = pk2(acc[t][0] + bv.x, acc[t][1] + bv.y);
      u.y = pk2(acc[t][2] + bv.z, acc[t][3] + bv.w);
      *reinterpret_cast<uint2*>(dst + o0) = u;
    }
  }
}

// ---------------- CSR build (once per call) ----------------
__global__ __launch_bounds__(256) void hist_kernel(
    const int* __restrict__ dst, int* __restrict__ deg)
{
  const int e = blockIdx.x * 256 + threadIdx.x;
  if (e < NE) atomicAdd(&deg[dst[e]], 1);
}

__global__ __launch_bounds__(256) void scan_kernel(int* deg, int* offsets)
{
  __shared__ int sums[256];
  const int t = threadIdx.x;
  const int per = (NN + 255) / 256;
  const int b = t * per;
  const int e = min(b + per, NN);
  int s = 0;
  for (int i = b; i < e; ++i) s += deg[i];
  sums[t] = s;
  __syncthreads();
  if (t == 0) {
    int run = 0;
    for (int i = 0; i < 256; ++i) { int v = sums[i]; sums[i] = run; run += v; }
  }
  __syncthreads();
  int run = sums[t];
  for (int i = b; i < e; ++i) {
    int v = deg[i];
    offsets[i] = run;
    deg[i] = run;
    run += v;
  }
  if (e == NN && b < NN) offsets[NN] = run;
}

__global__ __launch_bounds__(256) void fill_kernel(
    const int* __restrict__ src, const int* __restrict__ dst,
    const int* __restrict__ et, int* __restrict__ cursor,
    int* __restrict__ eidx)
{
  const int e = blockIdx.x * 256 + threadIdx.x;
  if (e < NE) {
    const int pos = atomicAdd(&cursor[dst[e]], 1);
    eidx[pos] = et[e] * NN + src[e];
  }
}

// ---------------- pull-mode aggregation ----------------
template<int BF16OUT>
__global__ __launch_bounds__(256) void aggregate_kernel(
    const unsigned short* __restrict__ hr,
    const int* __restrict__ offsets, const int* __restrict__ eidx,
    void* __restrict__ outv)
{
  const int node = blockIdx.x * 4 + (threadIdx.x >> 6);
  const int lane = threadIdx.x & 63;
  if (node >= NN) return;
  const int beg = offsets[node];
  const int end = offsets[node + 1];

  float a0 = 0.f, a1 = 0.f;
  int e = beg;
  for (; e + 3 < end; e += 4) {
    const int r0 = eidx[e], r1 = eidx[e + 1], r2 = eidx[e + 2], r3 = eidx[e + 3];
    const unsigned u0 = *reinterpret_cast<const unsigned*>(hr + (size_t)r0 * DD + lane * 2);
    const unsigned u1 = *reinterpret_cast<const unsigned*>(hr + (size_t)r1 * DD + lane * 2);
    const unsigned u2 = *reinterpret_cast<const unsigned*>(hr + (size_t)r2 * DD + lane * 2);
    const unsigned u3 = *reinterpret_cast<const unsigned*>(hr + (size_t)r3 * DD + lane * 2);
    a0 += (bflo(u0) + bflo(u1)) + (bflo(u2) + bflo(u3));
    a1 += (bfhi(u0) + bfhi(u1)) + (bfhi(u2) + bfhi(u3));
  }
  for (; e < end; ++e) {
    const unsigned u0 = *reinterpret_cast<const unsigned*>(hr + (size_t)eidx[e] * DD + lane * 2);
    a0 += bflo(u0);
    a1 += bfhi(u0);
  }

  if (BF16OUT) {
    unsigned* o = reinterpret_cast<unsigned*>((unsigned short*)outv + (size_t)node * DD + lane * 2);
    const unsigned u = *o;
    *o = pk2(bflo(u) + a0, bfhi(u) + a1);
  } else {
    float2* o = reinterpret_cast<float2*>((float*)outv + (size_t)node * DD + lane * 2);
    float2 v = *o;
    v.x += a0; v.y += a1;
    *o = v;
  }
}

extern "C" void kernel_launch(void* const* d_in, const int* in_sizes, int n_in,
                              void* d_out, int out_size, void* d_ws, size_t ws_size,
                              hipStream_t stream) {
  const int*   node_ids = (const int*)d_in[0];
  const int*   src   = (const int*)d_in[1];
  const int*   dst   = (const int*)d_in[2];
  const int*   etype = (const int*)d_in[3];
  const float* emb   = (const float*)d_in[4];
  const float* W1    = (const float*)d_in[5];
  const float* Ws1   = (const float*)d_in[6];
  const float* b1    = (const float*)d_in[7];
  const float* W2    = (const float*)d_in[8];
  const float* Ws2   = (const float*)d_in[9];
  const float* b2    = (const float*)d_in[10];

  // ws layout:
  //   hr     bf16 [R*NN*DD]       102.4 MB
  //   h1bf   bf16 [NN*DD]          12.8 MB
  //   WT     bf16 [18*DD*DD]        0.59 MB
  //   offsets i32 [NN+1], deg i32 [NN], eidx i32 [NE]
  char* p = (char*)d_ws;
  unsigned short* hr   = (unsigned short*)p;  p += (size_t)NR * NN * DD * 2;
  unsigned short* h1bf = (unsigned short*)p;  p += (size_t)NN * DD * 2;
  unsigned short* WT   = (unsigned short*)p;  p += (size_t)18 * DD * DD * 2;
  int* offsets         = (int*)p;             p += (size_t)(NN + 1) * 4;
  int* deg             = (int*)p;             p += (size_t)NN * 4;
  int* eidx            = (int*)p;

  const int eb = (NE + 255) / 256;
  dim3 tgrid((NN + 63) / 64, NR + 1);
  const int ab = (NN + 3) / 4;

  // weight convert + CSR build
  convw_kernel<<<dim3(DD, 18), 128, 0, stream>>>(W1, Ws1, W2, Ws2, WT);
  hipMemsetAsync(deg, 0, (size_t)NN * 4, stream);
  hist_kernel<<<eb, 256, 0, stream>>>(dst, deg);
  scan_kernel<<<1, 256, 0, stream>>>(deg, offsets);
  fill_kernel<<<eb, 256, 0, stream>>>(src, dst, etype, deg, eidx);

  // layer 1: A = emb[node_ids] (f32 gather), outputs bf16
  transform_mfma<1, 0><<<tgrid, 256, 0, stream>>>(emb, node_ids, WT, b1, hr, h1bf);
  aggregate_kernel<1><<<ab, 256, 0, stream>>>(hr, offsets, eidx, h1bf);
  // layer 2: A = h1 bf16, final output f32
  transform_mfma<0, 1><<<tgrid, 256, 0, stream>>>(h1bf, nullptr, WT + (size_t)9 * DD * DD, b2, hr, (float*)d_out);
  aggregate_kernel<0><<<ab, 256, 0, stream>>>(hr, offsets, eidx, (float*)d_out);
}

// Round 5
// 265.285 us; speedup vs baseline: 5.1546x; 1.3995x over previous
//
#include <hip/hip_runtime.h>
#include <hip/hip_bf16.h>

#define NN 50000
#define NE 600000
#define DD 128
#define NR 8
#define NCHUNK ((NN + 255) / 256)   // 196 scan blocks

typedef __attribute__((ext_vector_type(8))) short bf16x8;
typedef __attribute__((ext_vector_type(4))) float f32x4;

__device__ __forceinline__ unsigned short f2bf(float f) {
  __hip_bfloat16 h = __float2bfloat16(f);
  return *reinterpret_cast<unsigned short*>(&h);
}
__device__ __forceinline__ unsigned pk2(float lo, float hi) {
  return (unsigned)f2bf(lo) | ((unsigned)f2bf(hi) << 16);
}
__device__ __forceinline__ float bflo(unsigned u) { return __uint_as_float(u << 16); }
__device__ __forceinline__ float bfhi(unsigned u) { return __uint_as_float(u & 0xffff0000u); }

// ---------------- weight transpose+convert: WT[m][o][d] = bf16(W[m][d][o]) ----------------
__global__ __launch_bounds__(128) void convw_kernel(
    const float* __restrict__ W1, const float* __restrict__ Ws1,
    const float* __restrict__ W2, const float* __restrict__ Ws2,
    unsigned short* __restrict__ WT)
{
  const int m = blockIdx.y, o = blockIdx.x, d = threadIdx.x;
  const float* src;
  if (m < 8)       src = W1 + (size_t)m * DD * DD;
  else if (m == 8) src = Ws1;
  else if (m < 17) src = W2 + (size_t)(m - 9) * DD * DD;
  else             src = Ws2;
  WT[(size_t)m * DD * DD + o * DD + d] = f2bf(src[(size_t)d * DD + o]);
}

// ---------------- MFMA transform ----------------
template<int AF32, int OUTF32>
__global__ __launch_bounds__(256) void transform_mfma(
    const void* __restrict__ hin, const int* __restrict__ ids,
    const unsigned short* __restrict__ WT,   // this layer's 9 mats, [m][o][d] bf16
    const float* __restrict__ bias,
    unsigned short* __restrict__ hr,
    void* __restrict__ outSelf)
{
  __shared__ __align__(16) char ldsW[DD * DD * 2];   // 32 KB, XOR-swizzled

  const int r = blockIdx.y;
  const int rowBase = blockIdx.x * 64;
  const int tid = threadIdx.x;

  // stage WT[r] -> LDS: 2048 x 16B chunks (32 KB), swizzle byte ^= (o&7)<<4
  {
    const unsigned short* wsrc = WT + (size_t)r * DD * DD;
#pragma unroll
    for (int j = 0; j < 8; ++j) {
      const int i = tid + j * 256;          // i in [0, 2048)
      const int o = i >> 4, seg = i & 15;   // row o: 16 chunks of 16B = 256B
      uint4 v = *reinterpret_cast<const uint4*>(wsrc + o * DD + seg * 8);
      const int dstB = ((o << 8) + (seg << 4)) ^ ((o & 7) << 4);
      *reinterpret_cast<uint4*>(ldsW + dstB) = v;
    }
  }

  const int lane = tid & 63;
  const int w = tid >> 6;
  const int c = lane & 15;
  const int g = lane >> 4;
  const int n = rowBase + w * 16 + c;
  const int nld = (n < NN) ? n : (NN - 1);

  bf16x8 hfrag[4];
  if (AF32) {
    const int srcRow = ids[nld];
    const float* hrow = (const float*)hin + (size_t)srcRow * DD;
#pragma unroll
    for (int ks = 0; ks < 4; ++ks) {
      const float4 x = *reinterpret_cast<const float4*>(hrow + ks * 32 + g * 8);
      const float4 y = *reinterpret_cast<const float4*>(hrow + ks * 32 + g * 8 + 4);
      uint4 u;
      u.x = pk2(x.x, x.y); u.y = pk2(x.z, x.w);
      u.z = pk2(y.x, y.y); u.w = pk2(y.z, y.w);
      hfrag[ks] = *reinterpret_cast<bf16x8*>(&u);
    }
  } else {
    const unsigned short* hrow = (const unsigned short*)hin + (size_t)nld * DD;
#pragma unroll
    for (int ks = 0; ks < 4; ++ks) {
      uint4 u = *reinterpret_cast<const uint4*>(hrow + ks * 32 + g * 8);
      hfrag[ks] = *reinterpret_cast<bf16x8*>(&u);
    }
  }

  __syncthreads();

  f32x4 acc[8];
#pragma unroll
  for (int t = 0; t < 8; ++t) acc[t] = (f32x4){0.f, 0.f, 0.f, 0.f};

#pragma unroll
  for (int ks = 0; ks < 4; ++ks) {
#pragma unroll
    for (int t = 0; t < 8; ++t) {
      const int addr = (((t * 16 + c) << 8) + (ks << 6) + (g << 4)) ^ ((c & 7) << 4);
      bf16x8 a = *reinterpret_cast<const bf16x8*>(ldsW + addr);
      acc[t] = __builtin_amdgcn_mfma_f32_16x16x32_bf16(a, hfrag[ks], acc[t], 0, 0, 0);
    }
  }

  if (n >= NN) return;

  if (r < NR) {
    unsigned short* dst = hr + ((size_t)r * NN + n) * DD;
#pragma unroll
    for (int t = 0; t < 8; ++t) {
      const int o0 = t * 16 + g * 4;
      uint2 u;
      u.x = pk2(acc[t][0], acc[t][1]);
      u.y = pk2(acc[t][2], acc[t][3]);
      *reinterpret_cast<uint2*>(dst + o0) = u;
    }
  } else if (OUTF32) {
    float* dst = (float*)outSelf + (size_t)n * DD;
#pragma unroll
    for (int t = 0; t < 8; ++t) {
      const int o0 = t * 16 + g * 4;
      const float4 bv = *reinterpret_cast<const float4*>(bias + o0);
      float4 o;
      o.x = acc[t][0] + bv.x; o.y = acc[t][1] + bv.y;
      o.z = acc[t][2] + bv.z; o.w = acc[t][3] + bv.w;
      *reinterpret_cast<float4*>(dst + o0) = o;
    }
  } else {
    unsigned short* dst = (unsigned short*)outSelf + (size_t)n * DD;
#pragma unroll
    for (int t = 0; t < 8; ++t) {
      const int o0 = t * 16 + g * 4;
      const float4 bv = *reinterpret_cast<const float4*>(bias + o0);
      uint2 u;
      u.x = pk2(acc[t][0] + bv.x, acc[t][1] + bv.y);
      u.y = pk2(acc[t][2] + bv.z, acc[t][3] + bv.w);
      *reinterpret_cast<uint2*>(dst + o0) = u;
    }
  }
}

// ---------------- CSR build (once per call) ----------------
__global__ __launch_bounds__(256) void hist_kernel(
    const int* __restrict__ dst, int* __restrict__ deg)
{
  const int e = blockIdx.x * 256 + threadIdx.x;
  if (e < NE) atomicAdd(&deg[dst[e]], 1);
}

// phase 1: per-block (256-wide) sum of deg -> bsum[b]
__global__ __launch_bounds__(256) void bsum_kernel(
    const int* __restrict__ deg, int* __restrict__ bsum)
{
  __shared__ int tmp[256];
  const int t = threadIdx.x;
  const int i = blockIdx.x * 256 + t;
  tmp[t] = (i < NN) ? deg[i] : 0;
  __syncthreads();
#pragma unroll
  for (int off = 128; off > 0; off >>= 1) {
    if (t < off) tmp[t] += tmp[t + off];
    __syncthreads();
  }
  if (t == 0) bsum[blockIdx.x] = tmp[0];
}

// phase 2: 1-block exclusive scan of bsum[NCHUNK] -> bbase[NCHUNK]
__global__ __launch_bounds__(256) void bscan_kernel(
    const int* __restrict__ bsum, int* __restrict__ bbase)
{
  __shared__ int tmp[256];
  const int t = threadIdx.x;
  const int v = (t < NCHUNK) ? bsum[t] : 0;
  tmp[t] = v;
  __syncthreads();
#pragma unroll
  for (int off = 1; off < 256; off <<= 1) {
    const int x = (t >= off) ? tmp[t - off] : 0;
    __syncthreads();
    tmp[t] += x;
    __syncthreads();
  }
  if (t < NCHUNK) bbase[t] = tmp[t] - v;   // exclusive
}

// phase 3: per-block inclusive scan + base -> offsets[i], cursor (in-place in deg)
__global__ __launch_bounds__(256) void expand_kernel(
    int* deg, const int* __restrict__ bbase, int* __restrict__ offsets)
{
  __shared__ int tmp[256];
  const int t = threadIdx.x;
  const int i = blockIdx.x * 256 + t;
  const int v = (i < NN) ? deg[i] : 0;
  tmp[t] = v;
  __syncthreads();
#pragma unroll
  for (int off = 1; off < 256; off <<= 1) {
    const int x = (t >= off) ? tmp[t - off] : 0;
    __syncthreads();
    tmp[t] += x;
    __syncthreads();
  }
  const int base = bbase[blockIdx.x];
  const int excl = base + tmp[t] - v;
  if (i < NN) {
    offsets[i] = excl;
    deg[i] = excl;                  // fill cursor
    if (i == NN - 1) offsets[NN] = base + tmp[t];
  }
}

__global__ __launch_bounds__(256) void fill_kernel(
    const int* __restrict__ src, const int* __restrict__ dst,
    const int* __restrict__ et, int* __restrict__ cursor,
    int* __restrict__ eidx)
{
  const int e = blockIdx.x * 256 + threadIdx.x;
  if (e < NE) {
    const int pos = atomicAdd(&cursor[dst[e]], 1);
    eidx[pos] = et[e] * NN + src[e];
  }
}

// ---------------- pull-mode aggregation ----------------
template<int BF16OUT>
__global__ __launch_bounds__(256) void aggregate_kernel(
    const unsigned short* __restrict__ hr,
    const int* __restrict__ offsets, const int* __restrict__ eidx,
    void* __restrict__ outv)
{
  const int node = blockIdx.x * 4 + (threadIdx.x >> 6);
  const int lane = threadIdx.x & 63;
  if (node >= NN) return;
  const int beg = offsets[node];
  const int end = offsets[node + 1];

  float a0 = 0.f, a1 = 0.f;
  int e = beg;
  for (; e + 3 < end; e += 4) {
    const int r0 = eidx[e], r1 = eidx[e + 1], r2 = eidx[e + 2], r3 = eidx[e + 3];
    const unsigned u0 = *reinterpret_cast<const unsigned*>(hr + (size_t)r0 * DD + lane * 2);
    const unsigned u1 = *reinterpret_cast<const unsigned*>(hr + (size_t)r1 * DD + lane * 2);
    const unsigned u2 = *reinterpret_cast<const unsigned*>(hr + (size_t)r2 * DD + lane * 2);
    const unsigned u3 = *reinterpret_cast<const unsigned*>(hr + (size_t)r3 * DD + lane * 2);
    a0 += (bflo(u0) + bflo(u1)) + (bflo(u2) + bflo(u3));
    a1 += (bfhi(u0) + bfhi(u1)) + (bfhi(u2) + bfhi(u3));
  }
  for (; e < end; ++e) {
    const unsigned u0 = *reinterpret_cast<const unsigned*>(hr + (size_t)eidx[e] * DD + lane * 2);
    a0 += bflo(u0);
    a1 += bfhi(u0);
  }

  if (BF16OUT) {
    unsigned* o = reinterpret_cast<unsigned*>((unsigned short*)outv + (size_t)node * DD + lane * 2);
    const unsigned u = *o;
    *o = pk2(bflo(u) + a0, bfhi(u) + a1);
  } else {
    float2* o = reinterpret_cast<float2*>((float*)outv + (size_t)node * DD + lane * 2);
    float2 v = *o;
    v.x += a0; v.y += a1;
    *o = v;
  }
}

extern "C" void kernel_launch(void* const* d_in, const int* in_sizes, int n_in,
                              void* d_out, int out_size, void* d_ws, size_t ws_size,
                              hipStream_t stream) {
  const int*   node_ids = (const int*)d_in[0];
  const int*   src   = (const int*)d_in[1];
  const int*   dst   = (const int*)d_in[2];
  const int*   etype = (const int*)d_in[3];
  const float* emb   = (const float*)d_in[4];
  const float* W1    = (const float*)d_in[5];
  const float* Ws1   = (const float*)d_in[6];
  const float* b1    = (const float*)d_in[7];
  const float* W2    = (const float*)d_in[8];
  const float* Ws2   = (const float*)d_in[9];
  const float* b2    = (const float*)d_in[10];

  // ws layout:
  //   hr     bf16 [R*NN*DD]       102.4 MB
  //   h1bf   bf16 [NN*DD]          12.8 MB
  //   WT     bf16 [18*DD*DD]        0.59 MB
  //   offsets i32 [NN+1], deg i32 [NN], eidx i32 [NE], bsum/bbase i32 [256] each
  char* p = (char*)d_ws;
  unsigned short* hr   = (unsigned short*)p;  p += (size_t)NR * NN * DD * 2;
  unsigned short* h1bf = (unsigned short*)p;  p += (size_t)NN * DD * 2;
  unsigned short* WT   = (unsigned short*)p;  p += (size_t)18 * DD * DD * 2;
  int* offsets         = (int*)p;             p += (size_t)(NN + 1) * 4;
  int* deg             = (int*)p;             p += (size_t)NN * 4;
  int* eidx            = (int*)p;             p += (size_t)NE * 4;
  int* bsum            = (int*)p;             p += 256 * 4;
  int* bbase           = (int*)p;

  const int eb = (NE + 255) / 256;
  dim3 tgrid((NN + 63) / 64, NR + 1);
  const int ab = (NN + 3) / 4;

  // weight convert + CSR build
  convw_kernel<<<dim3(DD, 18), 128, 0, stream>>>(W1, Ws1, W2, Ws2, WT);
  hipMemsetAsync(deg, 0, (size_t)NN * 4, stream);
  hist_kernel<<<eb, 256, 0, stream>>>(dst, deg);
  bsum_kernel<<<NCHUNK, 256, 0, stream>>>(deg, bsum);
  bscan_kernel<<<1, 256, 0, stream>>>(bsum, bbase);
  expand_kernel<<<NCHUNK, 256, 0, stream>>>(deg, bbase, offsets);
  fill_kernel<<<eb, 256, 0, stream>>>(src, dst, etype, deg, eidx);

  // layer 1: A = emb[node_ids] (f32 gather), outputs bf16
  transform_mfma<1, 0><<<tgrid, 256, 0, stream>>>(emb, node_ids, WT, b1, hr, h1bf);
  aggregate_kernel<1><<<ab, 256, 0, stream>>>(hr, offsets, eidx, h1bf);
  // layer 2: A = h1 bf16, final output f32
  transform_mfma<0, 1><<<tgrid, 256, 0, stream>>>(h1bf, nullptr, WT + (size_t)9 * DD * DD, b2, hr, (float*)d_out);
  aggregate_kernel<0><<<ab, 256, 0, stream>>>(hr, offsets, eidx, (float*)d_out);
}